// Round 16
// baseline (751.493 us; speedup 1.0000x reference)
//
#include <hip/hip_runtime.h>
#include <hip/hip_bf16.h>
#include <math.h>

#define NN 100000
#define NG 12500

using f32x4 = __attribute__((ext_vector_type(4))) float;
using bf16x8 = __attribute__((ext_vector_type(8))) __bf16;

__device__ __forceinline__ float warp_sum(float v) {
#pragma unroll
  for (int o = 32; o >= 1; o >>= 1) v += __shfl_xor(v, o);
  return v;
}

__device__ __forceinline__ float elu_f(float x) {
  return x > 0.f ? x : expm1f(x);
}

__device__ __forceinline__ ushort f2bf(float f) {
  unsigned u = __float_as_uint(f);
  u += 0x7FFFu + ((u >> 16) & 1u);
  return (ushort)(u >> 16);
}

// HW packed fp32->bf16 RNE: lo16 = bf16(a), hi16 = bf16(b)
__device__ __forceinline__ unsigned pkbf(float a, float b) {
  unsigned r;
  asm("v_cvt_pk_bf16_f32 %0, %1, %2" : "=v"(r) : "v"(a), "v"(b));
  return r;
}

// swizzled byte offset into a [row][64 bf16] LDS tile (row stride 128 B)
__device__ __forceinline__ int swz(int row, int kbyte) {
  return row * 128 + (kbyte ^ ((row & 7) << 4));
}

__global__ __launch_bounds__(256) void cvt_bf16(const float* __restrict__ src,
                                                ushort* __restrict__ dst, int n4) {
  int i = blockIdx.x * 256 + threadIdx.x;
  if (i >= n4) return;
  float4 v = *reinterpret_cast<const float4*>(src + (size_t)i * 4);
  ushort4 o;
  o.x = f2bf(v.x); o.y = f2bf(v.y); o.z = f2bf(v.z); o.w = f2bf(v.w);
  *reinterpret_cast<ushort4*>(dst + (size_t)i * 4) = o;
}

#define MM(i, j, a, b) \
  acc[i][j] = __builtin_amdgcn_mfma_f32_16x16x32_bf16(a, b, acc[i][j], 0, 0, 0)

// B staging via global_load_lds (pre-swizzled source, linear LDS dest), 256thr
#define STAGEB(buf, base, rowoff, kt, K)                                        \
  do {                                                                          \
    _Pragma("unroll")                                                           \
    for (int u = 0; u < 4; ++u) {                                               \
      int unit = u * 256 + tid;                                                 \
      int drow = unit >> 3, dkg = unit & 7;                                     \
      const ushort* src = (base) + (size_t)((rowoff) + drow) * (K) + (kt) +     \
                          (((dkg * 16) ^ ((drow & 7) << 4)) >> 1);              \
      __builtin_amdgcn_global_load_lds(src, (buf) + u * 4096 + wid * 1024,      \
                                       16, 0, 0);                               \
    }                                                                           \
  } while (0)

// MFMA inner block over one staged K-step (both A,B bf16 in LDS), 64x64/wave
#define MFMABLOCK(AsB, BsB)                                                     \
  do {                                                                          \
    _Pragma("unroll")                                                           \
    for (int ks = 0; ks < 2; ++ks) {                                            \
      bf16x8 a0 = *reinterpret_cast<const bf16x8*>((AsB) + swz(wm + 0 + lr, ks * 64 + lg * 16));  \
      bf16x8 a1 = *reinterpret_cast<const bf16x8*>((AsB) + swz(wm + 16 + lr, ks * 64 + lg * 16)); \
      bf16x8 a2 = *reinterpret_cast<const bf16x8*>((AsB) + swz(wm + 32 + lr, ks * 64 + lg * 16)); \
      bf16x8 a3 = *reinterpret_cast<const bf16x8*>((AsB) + swz(wm + 48 + lr, ks * 64 + lg * 16)); \
      bf16x8 b0 = *reinterpret_cast<const bf16x8*>((BsB) + swz(wn + 0 + lr, ks * 64 + lg * 16));  \
      bf16x8 b1 = *reinterpret_cast<const bf16x8*>((BsB) + swz(wn + 16 + lr, ks * 64 + lg * 16)); \
      bf16x8 b2 = *reinterpret_cast<const bf16x8*>((BsB) + swz(wn + 32 + lr, ks * 64 + lg * 16)); \
      bf16x8 b3 = *reinterpret_cast<const bf16x8*>((BsB) + swz(wn + 48 + lr, ks * 64 + lg * 16)); \
      MM(0, 0, a0, b0); MM(0, 1, a0, b1); MM(0, 2, a0, b2); MM(0, 3, a0, b3);   \
      MM(1, 0, a1, b0); MM(1, 1, a1, b1); MM(1, 2, a1, b2); MM(1, 3, a1, b3);   \
      MM(2, 0, a2, b0); MM(2, 1, a2, b1); MM(2, 2, a2, b2); MM(2, 3, a2, b3);   \
      MM(3, 0, a3, b0); MM(3, 1, a3, b1); MM(3, 2, a3, b2); MM(3, 3, a3, b3);   \
    }                                                                           \
  } while (0)

// shared epilogue for 128x128 tiles (256 thr)
#define EPILOGUE(Cs)                                                            \
  do {                                                                          \
    _Pragma("unroll")                                                           \
    for (int j = 0; j < 4; ++j) {                                               \
      float bv = bias ? bias[col0 + wn + j * 16 + lr] : 0.f;                    \
      _Pragma("unroll")                                                         \
      for (int i = 0; i < 4; ++i)                                               \
        _Pragma("unroll")                                                       \
        for (int r = 0; r < 4; ++r) {                                           \
          float v = acc[i][j][r] + bv;                                          \
          if (RELU) v = fmaxf(v, 0.f);                                          \
          (Cs)[(wm + i * 16 + lg * 4 + r) * 136 + wn + j * 16 + lr] = f2bf(v);  \
        }                                                                       \
    }                                                                           \
    __syncthreads();                                                            \
    _Pragma("unroll")                                                           \
    for (int u = 0; u < 8; ++u) {                                               \
      int unit = tid + u * 256;                                                 \
      int r = unit >> 4, cg = unit & 15;                                        \
      int grow = row0 + r;                                                      \
      if (grow < M)                                                             \
        *reinterpret_cast<uint4*>(C + (size_t)grow * Nc + col0 + cg * 8) =      \
            *reinterpret_cast<const uint4*>((Cs) + r * 136 + cg * 8);           \
    }                                                                           \
  } while (0)

// ---------------------------------------------------------------------------
// GEMM1: A fp32 fused-convert, BM=128 x BN=512 full width (A read once).
// A loads NON-TEMPORAL: the 819MB zero-reuse A stream was evicting the 2MB B
// from L2/L3, forcing B to restage from HBM (1.56GB -> per-K-step 9.6k cyc,
// matching the measured 385us exactly). nt keeps B L2-resident.
// Both A and B double-buffered, ONE barrier per K-step after the MFMA block.
// 512 thr = 8 waves (2 row x 4 col of 64x128). LDS exactly 160KB.
// ---------------------------------------------------------------------------
template<bool RELU>
__global__ __launch_bounds__(512, 1) void gemm_f32x(
    const float* __restrict__ A, const ushort* __restrict__ B,
    const float* __restrict__ bias, ushort* __restrict__ C, int M, int K) {
  __shared__ char smem[163840];  // A 16KB x2 + B 64KB x2 == 160KB exactly
  char* As0 = smem;
  char* As1 = smem + 16384;
  char* Bs0 = smem + 32768;
  char* Bs1 = smem + 98304;
  const int tid = threadIdx.x, wid = tid >> 6, lane = tid & 63;
  const int lr = lane & 15, lg = lane >> 4;
  const int wm = (wid >> 2) * 64;    // wave row offset (0/64)
  const int wn = (wid & 3) * 128;    // wave col offset (0..384)
  const int row0 = blockIdx.x * 128;
  const int arow = tid >> 2, achunk = tid & 3;
  const bool aval = (row0 + arow) < M;
  const float* Aprow = A + (size_t)(row0 + arow) * K + achunk * 16;
  const int awb0 = swz(arow, achunk * 32), awb1 = swz(arow, achunk * 32 + 16);

  f32x4 rA0, rA1, rA2, rA3;

#define LOADA_X(kt)                                                     \
  do {                                                                  \
    if (aval) {                                                         \
      const f32x4* q = reinterpret_cast<const f32x4*>(Aprow + (kt));    \
      rA0 = __builtin_nontemporal_load(q);                              \
      rA1 = __builtin_nontemporal_load(q + 1);                          \
      rA2 = __builtin_nontemporal_load(q + 2);                          \
      rA3 = __builtin_nontemporal_load(q + 3);                          \
    }                                                                   \
  } while (0)

#define WRITEA_X(buf)                                                   \
  do {                                                                  \
    if (aval) {                                                         \
      uint4 w0, w1;                                                     \
      w0.x = pkbf(rA0.x, rA0.y); w0.y = pkbf(rA0.z, rA0.w);             \
      w0.z = pkbf(rA1.x, rA1.y); w0.w = pkbf(rA1.z, rA1.w);             \
      w1.x = pkbf(rA2.x, rA2.y); w1.y = pkbf(rA2.z, rA2.w);             \
      w1.z = pkbf(rA3.x, rA3.y); w1.w = pkbf(rA3.z, rA3.w);             \
      *reinterpret_cast<uint4*>((buf) + awb0) = w0;                     \
      *reinterpret_cast<uint4*>((buf) + awb1) = w1;                     \
    }                                                                   \
  } while (0)

// B tile 512 rows x 8 kgroups = 4096 units of 16B; 8 per thread (512 thr)
#define ISSUEB_X(buf, kt)                                               \
  do {                                                                  \
    _Pragma("unroll")                                                   \
    for (int u = 0; u < 8; ++u) {                                       \
      int unit = u * 512 + tid;                                         \
      int drow = unit >> 3, dkg = unit & 7;                             \
      const ushort* src = B + (size_t)drow * K + (kt) +                 \
                          (((dkg * 16) ^ ((drow & 7) << 4)) >> 1);      \
      __builtin_amdgcn_global_load_lds(src, (buf) + u * 8192 + wid * 1024, \
                                       16, 0, 0);                       \
    }                                                                   \
  } while (0)

  f32x4 acc[4][8] = {};
  // prologue: tile 0 fully staged
  LOADA_X(0);
  ISSUEB_X(Bs0, 0);
  WRITEA_X(As0);
  __syncthreads();
  int cur = 0;
  for (int kt = 0; kt < K; kt += 64) {
    char* Ac = cur ? As1 : As0;
    char* Bc = cur ? Bs1 : Bs0;
    char* An = cur ? As0 : As1;
    char* Bn = cur ? Bs0 : Bs1;
    const bool more = (kt + 64) < K;
    if (more) {
      LOADA_X(kt + 64);      // fp32 A -> regs (nt, in flight across MFMA)
      ISSUEB_X(Bn, kt + 64); // B glds -> nxt (in flight across MFMA)
    }
    __builtin_amdgcn_s_setprio(1);
#pragma unroll
    for (int ks = 0; ks < 2; ++ks) {
      bf16x8 a0 = *reinterpret_cast<const bf16x8*>(Ac + swz(wm + 0 + lr, ks * 64 + lg * 16));
      bf16x8 a1 = *reinterpret_cast<const bf16x8*>(Ac + swz(wm + 16 + lr, ks * 64 + lg * 16));
      bf16x8 a2 = *reinterpret_cast<const bf16x8*>(Ac + swz(wm + 32 + lr, ks * 64 + lg * 16));
      bf16x8 a3 = *reinterpret_cast<const bf16x8*>(Ac + swz(wm + 48 + lr, ks * 64 + lg * 16));
#pragma unroll
      for (int j = 0; j < 8; ++j) {
        bf16x8 bj = *reinterpret_cast<const bf16x8*>(Bc + swz(wn + j * 16 + lr, ks * 64 + lg * 16));
        MM(0, j, a0, bj); MM(1, j, a1, bj); MM(2, j, a2, bj); MM(3, j, a3, bj);
      }
    }
    __builtin_amdgcn_s_setprio(0);
    if (more) WRITEA_X(An);  // A(t+1) regs -> nxt LDS (latency hidden by MFMA)
    __syncthreads();         // single drain per K-step, AFTER compute
    cur ^= 1;
  }
#undef LOADA_X
#undef WRITEA_X
#undef ISSUEB_X
  // epilogue: 128 rows x 520-stride bf16 tile (133KB <= 160KB smem)
  ushort* Cs = reinterpret_cast<ushort*>(smem);
#pragma unroll
  for (int j = 0; j < 8; ++j) {
    float bv = bias[wn + j * 16 + lr];
#pragma unroll
    for (int i = 0; i < 4; ++i)
#pragma unroll
      for (int r = 0; r < 4; ++r) {
        float v = acc[i][j][r] + bv;
        if (RELU) v = fmaxf(v, 0.f);
        Cs[(wm + i * 16 + lg * 4 + r) * 520 + wn + j * 16 + lr] = f2bf(v);
      }
  }
  __syncthreads();
#pragma unroll
  for (int u = 0; u < 16; ++u) {
    int unit = tid + u * 512;
    int r = unit >> 6, cg = unit & 63;  // 128 rows x 64 groups of 8
    int grow = row0 + r;
    if (grow < M)
      *reinterpret_cast<uint4*>(C + (size_t)grow * 512 + cg * 8) =
          *reinterpret_cast<const uint4*>(Cs + r * 520 + cg * 8);
  }
}

// ---------------------------------------------------------------------------
// bf16 GEMM: both A and B staged via global_load_lds (R9 structure, 128x128).
// ---------------------------------------------------------------------------
template<bool RELU, int NC>
__global__ __launch_bounds__(256, 3) void gemm_glds(
    const ushort* __restrict__ A, const ushort* __restrict__ B,
    const float* __restrict__ bias, ushort* __restrict__ C,
    int M, int K, int Nc, int RB) {
  __shared__ char smem[128 * 136 * 2];
  int rb, cb;
  if (NC == 1) {
    rb = blockIdx.x; cb = 0;
  } else {
    int id = blockIdx.x;
    int x = id & 7, g = id >> 3;
    cb = g % NC;
    rb = (g / NC) * 8 + x;
  }
  if (rb >= RB) return;
  const int row0 = rb * 128, col0 = cb * 128;
  const int tid = threadIdx.x, wid = tid >> 6, lane = tid & 63;
  const int lr = lane & 15, lg = lane >> 4;
  const int wm = (wid >> 1) * 64, wn = (wid & 1) * 64;
  char* AsB = smem;
  char* BsB = smem + 16384;
  const int mrows = (M - row0 < 128) ? (M - row0) : 128;

#define STAGEA_G(buf, kt)                                                       \
  do {                                                                          \
    _Pragma("unroll")                                                           \
    for (int u = 0; u < 4; ++u) {                                               \
      int unit = u * 256 + tid;                                                 \
      int drow = unit >> 3, dkg = unit & 7;                                     \
      const ushort* src = A + (size_t)(row0 + drow) * K + (kt) +                \
                          (((dkg * 16) ^ ((drow & 7) << 4)) >> 1);              \
      if (drow < mrows)                                                         \
        __builtin_amdgcn_global_load_lds(src, (buf) + u * 4096 + wid * 1024,    \
                                         16, 0, 0);                             \
    }                                                                           \
  } while (0)

  f32x4 acc[4][4] = {};
  for (int kt = 0; kt < K; kt += 64) {
    STAGEA_G(AsB, kt);
    STAGEB(BsB, B, col0, kt, K);
    __syncthreads();
    MFMABLOCK(AsB, BsB);
    __syncthreads();
  }
#undef STAGEA_G
  ushort* Cs = reinterpret_cast<ushort*>(smem);
  EPILOGUE(Cs);
}

// x fp32 + xb16 bf16 dual-write; x[:,0:128]=cat_emb, x[:,128:256]=LN(v2)
__global__ __launch_bounds__(256) void ln_concat(const ushort* __restrict__ v2,
    const float* __restrict__ g, const float* __restrict__ b,
    const int* __restrict__ cat_ids, const float* __restrict__ cat_table,
    float* __restrict__ x, ushort* __restrict__ xb16) {
  int w = (blockIdx.x * blockDim.x + threadIdx.x) >> 6;
  int lane = threadIdx.x & 63;
  if (w >= NN) return;
  unsigned raw = *reinterpret_cast<const unsigned*>(v2 + (size_t)w * 128 + lane * 2);
  float ax = __uint_as_float(raw << 16);
  float ay = __uint_as_float(raw & 0xFFFF0000u);
  float s = ax + ay, s2 = ax * ax + ay * ay;
  s = warp_sum(s); s2 = warp_sum(s2);
  float mu = s * (1.f / 128.f);
  float var = s2 * (1.f / 128.f) - mu * mu;
  float rs = rsqrtf(var + 1e-5f);
  float2 gg = *reinterpret_cast<const float2*>(g + lane * 2);
  float2 bb = *reinterpret_cast<const float2*>(b + lane * 2);
  float2 o;
  o.x = (ax - mu) * rs * gg.x + bb.x;
  o.y = (ay - mu) * rs * gg.y + bb.y;
  *reinterpret_cast<float2*>(x + (size_t)w * 256 + 128 + lane * 2) = o;
  *reinterpret_cast<unsigned*>(xb16 + (size_t)w * 256 + 128 + lane * 2) = pkbf(o.x, o.y);
  int cid = cat_ids[w];
  float2 ce = *reinterpret_cast<const float2*>(cat_table + (size_t)cid * 128 + lane * 2);
  *reinterpret_cast<float2*>(x + (size_t)w * 256 + lane * 2) = ce;
  *reinterpret_cast<unsigned*>(xb16 + (size_t)w * 256 + lane * 2) = pkbf(ce.x, ce.y);
}

// fused GAT: scores + 8x8 softmax + aggregate + bias + elu + residual + LN.
template<int H>
__global__ __launch_bounds__(256) void gat_fused(const ushort* __restrict__ h,
    const float* __restrict__ asv, const float* __restrict__ adv,
    const float* __restrict__ bias, const float* __restrict__ lng,
    const float* __restrict__ lnb, float* __restrict__ x,
    ushort* __restrict__ xb16) {
  constexpr int C = 256 / H;
  constexpr int GROUP = C / 4;
  __shared__ __align__(16) float hs[4][8][256];
  __shared__ float attS[4][8][H], attD[4][8][H];
  const int wid = threadIdx.x >> 6, lane = threadIdx.x & 63;
  const int g = blockIdx.x * 4 + wid;
  const int base = g * 8;
  const int hd = lane / GROUP;
  float4 as4 = *reinterpret_cast<const float4*>(asv + lane * 4);
  float4 ad4 = *reinterpret_cast<const float4*>(adv + lane * 4);
#pragma unroll
  for (int i = 0; i < 8; ++i) {
    uint2 raw = *reinterpret_cast<const uint2*>(h + (size_t)(base + i) * 256 + lane * 4);
    float f0 = __uint_as_float(raw.x << 16);
    float f1 = __uint_as_float(raw.x & 0xFFFF0000u);
    float f2 = __uint_as_float(raw.y << 16);
    float f3 = __uint_as_float(raw.y & 0xFFFF0000u);
    *reinterpret_cast<float4*>(&hs[wid][i][lane * 4]) = make_float4(f0, f1, f2, f3);
    float ps = f0 * as4.x + f1 * as4.y + f2 * as4.z + f3 * as4.w;
    float pd = f0 * ad4.x + f1 * ad4.y + f2 * ad4.z + f3 * ad4.w;
#pragma unroll
    for (int o = GROUP / 2; o >= 1; o >>= 1) {
      ps += __shfl_xor(ps, o);
      pd += __shfl_xor(pd, o);
    }
    if ((lane & (GROUP - 1)) == 0) {
      attS[wid][i][hd] = ps;
      attD[wid][i][hd] = pd;
    }
  }
  __syncthreads();
  const float4 gv = *reinterpret_cast<const float4*>(lng + lane * 4);
  const float4 bv = *reinterpret_cast<const float4*>(lnb + lane * 4);
  const float4 biasv = *reinterpret_cast<const float4*>(bias + lane * 4);
  for (int i = 0; i < 8; ++i) {
    float ad = attD[wid][i][hd];
    float e[8];
    float mx = -1e30f;
#pragma unroll
    for (int j = 0; j < 8; ++j) {
      float v = attS[wid][j][hd] + ad;
      v = v > 0.f ? v : 0.2f * v;
      e[j] = v;
      mx = fmaxf(mx, v);
    }
    float sum = 0.f;
#pragma unroll
    for (int j = 0; j < 8; ++j) { e[j] = expf(e[j] - mx); sum += e[j]; }
    float inv = 1.f / (sum + 1e-16f);
    float a0 = 0, a1 = 0, a2 = 0, a3 = 0;
#pragma unroll
    for (int j = 0; j < 8; ++j) {
      float wj = e[j] * inv;
      float4 hv = *reinterpret_cast<const float4*>(&hs[wid][j][lane * 4]);
      a0 += wj * hv.x; a1 += wj * hv.y; a2 += wj * hv.z; a3 += wj * hv.w;
    }
    float4 xr = *reinterpret_cast<const float4*>(x + (size_t)(base + i) * 256 + lane * 4);
    float v0 = elu_f(a0 + biasv.x) + xr.x;
    float v1 = elu_f(a1 + biasv.y) + xr.y;
    float v2 = elu_f(a2 + biasv.z) + xr.z;
    float v3 = elu_f(a3 + biasv.w) + xr.w;
    float s = v0 + v1 + v2 + v3;
    float s2 = v0 * v0 + v1 * v1 + v2 * v2 + v3 * v3;
    s = warp_sum(s); s2 = warp_sum(s2);
    float mu = s * (1.f / 256.f);
    float var = s2 * (1.f / 256.f) - mu * mu;
    float rs = rsqrtf(var + 1e-5f);
    float4 o;
    o.x = (v0 - mu) * rs * gv.x + bv.x;
    o.y = (v1 - mu) * rs * gv.y + bv.y;
    o.z = (v2 - mu) * rs * gv.z + bv.z;
    o.w = (v3 - mu) * rs * gv.w + bv.w;
    *reinterpret_cast<float4*>(x + (size_t)(base + i) * 256 + lane * 4) = o;
    uint2 ob;
    ob.x = pkbf(o.x, o.y);
    ob.y = pkbf(o.z, o.w);
    *reinterpret_cast<uint2*>(xb16 + (size_t)(base + i) * 256 + lane * 4) = ob;
  }
}

__global__ __launch_bounds__(256) void pool_readout(const float* __restrict__ x,
    const float* __restrict__ rw, const float* __restrict__ rb,
    float* __restrict__ out) {
  int g = (blockIdx.x * blockDim.x + threadIdx.x) >> 6;
  int lane = threadIdx.x & 63;
  if (g >= NG) return;
  float a0 = 0, a1 = 0, a2 = 0, a3 = 0;
#pragma unroll
  for (int j = 0; j < 8; ++j) {
    float4 v = *reinterpret_cast<const float4*>(x + (size_t)(g * 8 + j) * 256 + lane * 4);
    a0 += v.x; a1 += v.y; a2 += v.z; a3 += v.w;
  }
  float4 w = *reinterpret_cast<const float4*>(rw + lane * 4);
  float p = (a0 * w.x + a1 * w.y + a2 * w.z + a3 * w.w) * 0.125f;
  p = warp_sum(p);
  if (lane == 0) out[g] = 1.f / (1.f + expf(-(p + rb[0])));
}

extern "C" void kernel_launch(void* const* d_in, const int* in_sizes, int n_in,
                              void* d_out, int out_size, void* d_ws, size_t ws_size,
                              hipStream_t stream) {
  const int* cat_ids = (const int*)d_in[0];
  const float* vf = (const float*)d_in[1];
  const float* cat_table = (const float*)d_in[4];
  const float* vp_w1 = (const float*)d_in[5];
  const float* vp_b1 = (const float*)d_in[6];
  const float* vp_w2 = (const float*)d_in[7];
  const float* vp_b2 = (const float*)d_in[8];
  const float* vp_lng = (const float*)d_in[9];
  const float* vp_lnb = (const float*)d_in[10];
  const float* c0_w = (const float*)d_in[11];
  const float* c0_as = (const float*)d_in[12];
  const float* c0_ad = (const float*)d_in[13];
  const float* c0_b = (const float*)d_in[14];
  const float* ln0_g = (const float*)d_in[15];
  const float* ln0_b = (const float*)d_in[16];
  const float* c1_w = (const float*)d_in[17];
  const float* c1_as = (const float*)d_in[18];
  const float* c1_ad = (const float*)d_in[19];
  const float* c1_b = (const float*)d_in[20];
  const float* ln1_g = (const float*)d_in[21];
  const float* ln1_b = (const float*)d_in[22];
  const float* ro_w = (const float*)d_in[23];
  const float* ro_b = (const float*)d_in[24];
  float* out = (float*)d_out;

  char* ws = (char*)d_ws;
  ushort* w1b = (ushort*)ws;   ws += (size_t)512 * 2048 * 2;
  ushort* w2b = (ushort*)ws;   ws += (size_t)128 * 512 * 2;
  ushort* c0wb = (ushort*)ws;  ws += (size_t)256 * 256 * 2;
  ushort* c1wb = (ushort*)ws;  ws += (size_t)256 * 256 * 2;
  ushort* v1b = (ushort*)ws;   ws += (size_t)NN * 512 * 2;
  ushort* v2b = (ushort*)ws;   ws += (size_t)NN * 128 * 2;
  float* xb = (float*)ws;      ws += (size_t)NN * 256 * 4;
  ushort* xbb = (ushort*)ws;   ws += (size_t)NN * 256 * 2;
  ushort* hbb = (ushort*)ws;

  dim3 b256(256), b512(512);
  const int RB = (NN + 127) / 128;          // 782
  const int RBpad = ((RB + 7) / 8) * 8;     // 784

  cvt_bf16<<<1024, b256, 0, stream>>>(vp_w1, w1b, 512 * 2048 / 4);
  cvt_bf16<<<64, b256, 0, stream>>>(vp_w2, w2b, 128 * 512 / 4);
  cvt_bf16<<<64, b256, 0, stream>>>(c0_w, c0wb, 256 * 256 / 4);
  cvt_bf16<<<64, b256, 0, stream>>>(c1_w, c1wb, 256 * 256 / 4);

  // v1 = relu(vf @ w1^T + b1): 128x512 full-width, nt A loads, dbuf A+B
  gemm_f32x<true><<<RB, b512, 0, stream>>>(vf, w1b, vp_b1, v1b, NN, 2048);
  // v2 = v1 @ w2^T + b2
  gemm_glds<false, 1><<<RB, b256, 0, stream>>>(v1b, w2b, vp_b2, v2b,
                                               NN, 512, 128, RB);
  ln_concat<<<(NN * 64 + 255) / 256, b256, 0, stream>>>(v2b, vp_lng, vp_lnb,
                                                        cat_ids, cat_table, xb, xbb);

  gemm_glds<false, 2><<<RBpad * 2, b256, 0, stream>>>(xbb, c0wb, nullptr, hbb,
                                                      NN, 256, 256, RB);
  gat_fused<4><<<NG / 4, b256, 0, stream>>>(hbb, c0_as, c0_ad, c0_b, ln0_g, ln0_b, xb, xbb);

  gemm_glds<false, 2><<<RBpad * 2, b256, 0, stream>>>(xbb, c1wb, nullptr, hbb,
                                                      NN, 256, 256, RB);
  gat_fused<1><<<NG / 4, b256, 0, stream>>>(hbb, c1_as, c1_ad, c1_b, ln1_g, ln1_b, xb, xbb);

  pool_readout<<<NG / 4, b256, 0, stream>>>(xb, ro_w, ro_b, out);
}

// Round 17
// 596.375 us; speedup vs baseline: 1.2601x; 1.2601x over previous
//
#include <hip/hip_runtime.h>
#include <hip/hip_bf16.h>
#include <math.h>

#define NN 100000
#define NG 12500

using f32x4 = __attribute__((ext_vector_type(4))) float;
using bf16x8 = __attribute__((ext_vector_type(8))) __bf16;

__device__ __forceinline__ float warp_sum(float v) {
#pragma unroll
  for (int o = 32; o >= 1; o >>= 1) v += __shfl_xor(v, o);
  return v;
}

__device__ __forceinline__ float elu_f(float x) {
  return x > 0.f ? x : expm1f(x);
}

__device__ __forceinline__ ushort f2bf(float f) {
  unsigned u = __float_as_uint(f);
  u += 0x7FFFu + ((u >> 16) & 1u);
  return (ushort)(u >> 16);
}

__device__ __forceinline__ float bf2f_lo(unsigned u) {
  return __uint_as_float(u << 16);
}
__device__ __forceinline__ float bf2f_hi(unsigned u) {
  return __uint_as_float(u & 0xFFFF0000u);
}

// HW packed fp32->bf16 RNE: lo16 = bf16(a), hi16 = bf16(b)
__device__ __forceinline__ unsigned pkbf(float a, float b) {
  unsigned r;
  asm("v_cvt_pk_bf16_f32 %0, %1, %2" : "=v"(r) : "v"(a), "v"(b));
  return r;
}

// swizzled byte offset into a [row][64 bf16] LDS tile (row stride 128 B)
__device__ __forceinline__ int swz(int row, int kbyte) {
  return row * 128 + (kbyte ^ ((row & 7) << 4));
}

__global__ __launch_bounds__(256) void cvt_bf16(const float* __restrict__ src,
                                                ushort* __restrict__ dst, int n4) {
  int i = blockIdx.x * 256 + threadIdx.x;
  if (i >= n4) return;
  float4 v = *reinterpret_cast<const float4*>(src + (size_t)i * 4);
  ushort4 o;
  o.x = f2bf(v.x); o.y = f2bf(v.y); o.z = f2bf(v.z); o.w = f2bf(v.w);
  *reinterpret_cast<ushort4*>(dst + (size_t)i * 4) = o;
}

#define MM(i, j, a, b) \
  acc[i][j] = __builtin_amdgcn_mfma_f32_16x16x32_bf16(a, b, acc[i][j], 0, 0, 0)

// B staging via global_load_lds (pre-swizzled source, linear LDS dest), 256thr
#define STAGEB(buf, base, rowoff, kt, K)                                        \
  do {                                                                          \
    _Pragma("unroll")                                                           \
    for (int u = 0; u < 4; ++u) {                                               \
      int unit = u * 256 + tid;                                                 \
      int drow = unit >> 3, dkg = unit & 7;                                     \
      const ushort* src = (base) + (size_t)((rowoff) + drow) * (K) + (kt) +     \
                          (((dkg * 16) ^ ((drow & 7) << 4)) >> 1);              \
      __builtin_amdgcn_global_load_lds(src, (buf) + u * 4096 + wid * 1024,      \
                                       16, 0, 0);                               \
    }                                                                           \
  } while (0)

// MFMA inner block over one staged K-step (both A,B bf16 in LDS), 64x64/wave
#define MFMABLOCK(AsB, BsB)                                                     \
  do {                                                                          \
    _Pragma("unroll")                                                           \
    for (int ks = 0; ks < 2; ++ks) {                                            \
      bf16x8 a0 = *reinterpret_cast<const bf16x8*>((AsB) + swz(wm + 0 + lr, ks * 64 + lg * 16));  \
      bf16x8 a1 = *reinterpret_cast<const bf16x8*>((AsB) + swz(wm + 16 + lr, ks * 64 + lg * 16)); \
      bf16x8 a2 = *reinterpret_cast<const bf16x8*>((AsB) + swz(wm + 32 + lr, ks * 64 + lg * 16)); \
      bf16x8 a3 = *reinterpret_cast<const bf16x8*>((AsB) + swz(wm + 48 + lr, ks * 64 + lg * 16)); \
      bf16x8 b0 = *reinterpret_cast<const bf16x8*>((BsB) + swz(wn + 0 + lr, ks * 64 + lg * 16));  \
      bf16x8 b1 = *reinterpret_cast<const bf16x8*>((BsB) + swz(wn + 16 + lr, ks * 64 + lg * 16)); \
      bf16x8 b2 = *reinterpret_cast<const bf16x8*>((BsB) + swz(wn + 32 + lr, ks * 64 + lg * 16)); \
      bf16x8 b3 = *reinterpret_cast<const bf16x8*>((BsB) + swz(wn + 48 + lr, ks * 64 + lg * 16)); \
      MM(0, 0, a0, b0); MM(0, 1, a0, b1); MM(0, 2, a0, b2); MM(0, 3, a0, b3);   \
      MM(1, 0, a1, b0); MM(1, 1, a1, b1); MM(1, 2, a1, b2); MM(1, 3, a1, b3);   \
      MM(2, 0, a2, b0); MM(2, 1, a2, b1); MM(2, 2, a2, b2); MM(2, 3, a2, b3);   \
      MM(3, 0, a3, b0); MM(3, 1, a3, b1); MM(3, 2, a3, b2); MM(3, 3, a3, b3);   \
    }                                                                           \
  } while (0)

// shared epilogue for 128x128 tiles (256 thr)
#define EPILOGUE(Cs)                                                            \
  do {                                                                          \
    _Pragma("unroll")                                                           \
    for (int j = 0; j < 4; ++j) {                                               \
      float bv = bias ? bias[col0 + wn + j * 16 + lr] : 0.f;                    \
      _Pragma("unroll")                                                         \
      for (int i = 0; i < 4; ++i)                                               \
        _Pragma("unroll")                                                       \
        for (int r = 0; r < 4; ++r) {                                           \
          float v = acc[i][j][r] + bv;                                          \
          if (RELU) v = fmaxf(v, 0.f);                                          \
          (Cs)[(wm + i * 16 + lg * 4 + r) * 136 + wn + j * 16 + lr] = f2bf(v);  \
        }                                                                       \
    }                                                                           \
    __syncthreads();                                                            \
    _Pragma("unroll")                                                           \
    for (int u = 0; u < 8; ++u) {                                               \
      int unit = tid + u * 256;                                                 \
      int r = unit >> 4, cg = unit & 15;                                        \
      int grow = row0 + r;                                                      \
      if (grow < M)                                                             \
        *reinterpret_cast<uint4*>(C + (size_t)grow * Nc + col0 + cg * 8) =      \
            *reinterpret_cast<const uint4*>((Cs) + r * 136 + cg * 8);           \
    }                                                                           \
  } while (0)

// ---------------------------------------------------------------------------
// GEMM1 (R13 config, best measured): A fp32 fused-convert, BM=128 x BN=512.
// B double-buffered via glds, drain after MFMA. 512 thr = 8 waves.
// ---------------------------------------------------------------------------
template<bool RELU>
__global__ __launch_bounds__(512, 1) void gemm_f32p(
    const float* __restrict__ A, const ushort* __restrict__ B,
    const float* __restrict__ bias, ushort* __restrict__ C, int M, int K) {
  __shared__ char smem[16384 + 2 * 65536];
  char* AsB = smem;
  char* Bs0 = smem + 16384;
  char* Bs1 = smem + 16384 + 65536;
  const int tid = threadIdx.x, wid = tid >> 6, lane = tid & 63;
  const int lr = lane & 15, lg = lane >> 4;
  const int wm = (wid >> 2) * 64;
  const int wn = (wid & 3) * 128;
  const int row0 = blockIdx.x * 128;
  const int arow = tid >> 2, achunk = tid & 3;
  const bool aval = (row0 + arow) < M;
  const float* Aprow = A + (size_t)(row0 + arow) * K + achunk * 16;
  const int awb0 = swz(arow, achunk * 32), awb1 = swz(arow, achunk * 32 + 16);

  float4 rA0, rA1, rA2, rA3;

#define LOADA_P(kt)                                                     \
  do {                                                                  \
    if (aval && (kt) < K) {                                             \
      const float* q = Aprow + (kt);                                    \
      rA0 = *reinterpret_cast<const float4*>(q);                        \
      rA1 = *reinterpret_cast<const float4*>(q + 4);                    \
      rA2 = *reinterpret_cast<const float4*>(q + 8);                    \
      rA3 = *reinterpret_cast<const float4*>(q + 12);                   \
    }                                                                   \
  } while (0)

#define ISSUEB_P(buf, kt)                                               \
  do {                                                                  \
    _Pragma("unroll")                                                   \
    for (int u = 0; u < 8; ++u) {                                       \
      int unit = u * 512 + tid;                                         \
      int drow = unit >> 3, dkg = unit & 7;                             \
      const ushort* src = B + (size_t)drow * K + (kt) +                 \
                          (((dkg * 16) ^ ((drow & 7) << 4)) >> 1);      \
      __builtin_amdgcn_global_load_lds(src, (buf) + u * 8192 + wid * 1024, \
                                       16, 0, 0);                       \
    }                                                                   \
  } while (0)

  f32x4 acc[4][8] = {};
  LOADA_P(0);
  ISSUEB_P(Bs0, 0);
  int cur = 0;
  for (int kt = 0; kt < K; kt += 64) {
    if (aval) {
      uint4 w0, w1;
      w0.x = pkbf(rA0.x, rA0.y); w0.y = pkbf(rA0.z, rA0.w);
      w0.z = pkbf(rA1.x, rA1.y); w0.w = pkbf(rA1.z, rA1.w);
      w1.x = pkbf(rA2.x, rA2.y); w1.y = pkbf(rA2.z, rA2.w);
      w1.z = pkbf(rA3.x, rA3.y); w1.w = pkbf(rA3.z, rA3.w);
      *reinterpret_cast<uint4*>(AsB + awb0) = w0;
      *reinterpret_cast<uint4*>(AsB + awb1) = w1;
    }
    __syncthreads();
    char* BsB = cur ? Bs1 : Bs0;
    char* Bnxt = cur ? Bs0 : Bs1;
    if (kt + 64 < K) ISSUEB_P(Bnxt, kt + 64);
    LOADA_P(kt + 64);
#pragma unroll
    for (int ks = 0; ks < 2; ++ks) {
      bf16x8 a0 = *reinterpret_cast<const bf16x8*>(AsB + swz(wm + 0 + lr, ks * 64 + lg * 16));
      bf16x8 a1 = *reinterpret_cast<const bf16x8*>(AsB + swz(wm + 16 + lr, ks * 64 + lg * 16));
      bf16x8 a2 = *reinterpret_cast<const bf16x8*>(AsB + swz(wm + 32 + lr, ks * 64 + lg * 16));
      bf16x8 a3 = *reinterpret_cast<const bf16x8*>(AsB + swz(wm + 48 + lr, ks * 64 + lg * 16));
#pragma unroll
      for (int j = 0; j < 8; ++j) {
        bf16x8 bj = *reinterpret_cast<const bf16x8*>(BsB + swz(wn + j * 16 + lr, ks * 64 + lg * 16));
        MM(0, j, a0, bj); MM(1, j, a1, bj); MM(2, j, a2, bj); MM(3, j, a3, bj);
      }
    }
    __syncthreads();
    cur ^= 1;
  }
#undef LOADA_P
#undef ISSUEB_P
  ushort* Cs = reinterpret_cast<ushort*>(smem);
#pragma unroll
  for (int j = 0; j < 8; ++j) {
    float bv = bias[wn + j * 16 + lr];
#pragma unroll
    for (int i = 0; i < 4; ++i)
#pragma unroll
      for (int r = 0; r < 4; ++r) {
        float v = acc[i][j][r] + bv;
        if (RELU) v = fmaxf(v, 0.f);
        Cs[(wm + i * 16 + lg * 4 + r) * 520 + wn + j * 16 + lr] = f2bf(v);
      }
  }
  __syncthreads();
#pragma unroll
  for (int u = 0; u < 16; ++u) {
    int unit = tid + u * 512;
    int r = unit >> 6, cg = unit & 63;
    int grow = row0 + r;
    if (grow < M)
      *reinterpret_cast<uint4*>(C + (size_t)grow * 512 + cg * 8) =
          *reinterpret_cast<const uint4*>(Cs + r * 520 + cg * 8);
  }
}

// ---------------------------------------------------------------------------
// bf16 GEMM: both A and B staged via global_load_lds (R9 structure, 128x128).
// ---------------------------------------------------------------------------
template<bool RELU, int NC>
__global__ __launch_bounds__(256, 3) void gemm_glds(
    const ushort* __restrict__ A, const ushort* __restrict__ B,
    const float* __restrict__ bias, ushort* __restrict__ C,
    int M, int K, int Nc, int RB) {
  __shared__ char smem[128 * 136 * 2];
  int rb, cb;
  if (NC == 1) {
    rb = blockIdx.x; cb = 0;
  } else {
    int id = blockIdx.x;
    int x = id & 7, g = id >> 3;
    cb = g % NC;
    rb = (g / NC) * 8 + x;
  }
  if (rb >= RB) return;
  const int row0 = rb * 128, col0 = cb * 128;
  const int tid = threadIdx.x, wid = tid >> 6, lane = tid & 63;
  const int lr = lane & 15, lg = lane >> 4;
  const int wm = (wid >> 1) * 64, wn = (wid & 1) * 64;
  char* AsB = smem;
  char* BsB = smem + 16384;
  const int mrows = (M - row0 < 128) ? (M - row0) : 128;

#define STAGEA_G(buf, kt)                                                       \
  do {                                                                          \
    _Pragma("unroll")                                                           \
    for (int u = 0; u < 4; ++u) {                                               \
      int unit = u * 256 + tid;                                                 \
      int drow = unit >> 3, dkg = unit & 7;                                     \
      const ushort* src = A + (size_t)(row0 + drow) * K + (kt) +                \
                          (((dkg * 16) ^ ((drow & 7) << 4)) >> 1);              \
      if (drow < mrows)                                                         \
        __builtin_amdgcn_global_load_lds(src, (buf) + u * 4096 + wid * 1024,    \
                                         16, 0, 0);                             \
    }                                                                           \
  } while (0)

  f32x4 acc[4][4] = {};
  for (int kt = 0; kt < K; kt += 64) {
    STAGEA_G(AsB, kt);
    STAGEB(BsB, B, col0, kt, K);
    __syncthreads();
    MFMABLOCK(AsB, BsB);
    __syncthreads();
  }
#undef STAGEA_G
  ushort* Cs = reinterpret_cast<ushort*>(smem);
  EPILOGUE(Cs);
}

// ---------------------------------------------------------------------------
// GEMM2 + fused LN + concat: A=v1b (bf16), B=w2b, out xbb[*,128:256]=LN(A@B+b),
// xbb[*,0:128]=catb[cat_ids]. 128x128 tile, NC=1.
// ---------------------------------------------------------------------------
__global__ __launch_bounds__(256, 3) void gemm_ln(
    const ushort* __restrict__ A, const ushort* __restrict__ B,
    const float* __restrict__ bias, const float* __restrict__ lng,
    const float* __restrict__ lnb, const int* __restrict__ cat_ids,
    const ushort* __restrict__ catb, ushort* __restrict__ xbb,
    int M, int K, int RB) {
  __shared__ char smem[128 * 136 * 2 + 1024];
  float* gA = reinterpret_cast<float*>(smem + 34816);
  float* bA = gA + 128;
  const int rb = blockIdx.x;
  if (rb >= RB) return;
  const int row0 = rb * 128;
  const int tid = threadIdx.x, wid = tid >> 6, lane = tid & 63;
  const int lr = lane & 15, lg = lane >> 4;
  const int wm = (wid >> 1) * 64, wn = (wid & 1) * 64;
  char* AsB = smem;
  char* BsB = smem + 16384;
  const int mrows = (M - row0 < 128) ? (M - row0) : 128;
  if (tid < 128) {
    gA[tid] = lng[tid];
    bA[tid] = lnb[tid];
  }

  f32x4 acc[4][4] = {};
  for (int kt = 0; kt < K; kt += 64) {
#pragma unroll
    for (int u = 0; u < 4; ++u) {
      int unit = u * 256 + tid;
      int drow = unit >> 3, dkg = unit & 7;
      const ushort* src = A + (size_t)(row0 + drow) * K + kt +
                          (((dkg * 16) ^ ((drow & 7) << 4)) >> 1);
      if (drow < mrows)
        __builtin_amdgcn_global_load_lds(src, AsB + u * 4096 + wid * 1024, 16, 0, 0);
    }
    STAGEB(BsB, B, 0, kt, K);
    __syncthreads();
    MFMABLOCK(AsB, BsB);
    __syncthreads();
  }
  // acc -> Cs bf16 (stride 136), + bias
  ushort* Cs = reinterpret_cast<ushort*>(smem);
#pragma unroll
  for (int j = 0; j < 4; ++j) {
    float bv = bias[wn + j * 16 + lr];
#pragma unroll
    for (int i = 0; i < 4; ++i)
#pragma unroll
      for (int r = 0; r < 4; ++r)
        Cs[(wm + i * 16 + lg * 4 + r) * 136 + wn + j * 16 + lr] =
            f2bf(acc[i][j][r] + bv);
  }
  __syncthreads();
  if (tid < 128) {
    // thread = row: LN over 128 bf16 from Cs, write xbb[row][128:256]
    int grow = row0 + tid;
    if (grow < M) {
      const uint4* rp = reinterpret_cast<const uint4*>(Cs + tid * 136);
      float vals[128];
      float s = 0.f, s2 = 0.f;
#pragma unroll
      for (int q = 0; q < 16; ++q) {
        uint4 v = rp[q];
#pragma unroll
        for (int h = 0; h < 4; ++h) {
          unsigned u = (&v.x)[h];
          float f0 = bf2f_lo(u), f1 = bf2f_hi(u);
          vals[q * 8 + h * 2] = f0; vals[q * 8 + h * 2 + 1] = f1;
          s += f0 + f1; s2 += f0 * f0 + f1 * f1;
        }
      }
      float mu = s * (1.f / 128.f);
      float var = s2 * (1.f / 128.f) - mu * mu;
      float rs = rsqrtf(var + 1e-5f);
      uint4 ov[8];
#pragma unroll
      for (int q = 0; q < 8; ++q) {
#pragma unroll
        for (int h = 0; h < 4; ++h) {
          int d = q * 16 + h * 4;
          float o0 = (vals[d] - mu) * rs * gA[d] + bA[d];
          float o1 = (vals[d + 1] - mu) * rs * gA[d + 1] + bA[d + 1];
          float o2 = (vals[d + 2] - mu) * rs * gA[d + 2] + bA[d + 2];
          float o3 = (vals[d + 3] - mu) * rs * gA[d + 3] + bA[d + 3];
          (&ov[q].x)[h] = 0;  // init
          (&ov[q].x)[h] = pkbf(o0, o1) & 0xFFFFFFFFu;
          // pack pairs: need two unsigneds per 4 floats
          (void)o2; (void)o3;
        }
      }
      // repack properly: 128 bf16 = 16 uint4; do it directly
      ushort* dst = xbb + (size_t)grow * 256 + 128;
#pragma unroll
      for (int q = 0; q < 16; ++q) {
        uint4 w;
#pragma unroll
        for (int h = 0; h < 4; ++h) {
          int d = q * 8 + h * 2;
          float o0 = (vals[d] - mu) * rs * gA[d] + bA[d];
          float o1 = (vals[d + 1] - mu) * rs * gA[d + 1] + bA[d + 1];
          (&w.x)[h] = pkbf(o0, o1);
        }
        *reinterpret_cast<uint4*>(dst + q * 8) = w;
      }
    }
  } else {
    // thread-128 = row: gather cat embedding (bf16) -> xbb[row][0:128]
    int r = tid - 128;
    int grow = row0 + r;
    if (grow < M) {
      int cid = cat_ids[grow];
      const uint4* sp = reinterpret_cast<const uint4*>(catb + (size_t)cid * 128);
      uint4* dp = reinterpret_cast<uint4*>(xbb + (size_t)grow * 256);
#pragma unroll
      for (int q = 0; q < 16; ++q) dp[q] = sp[q];
    }
  }
}

// fused GAT: scores + 8x8 softmax + aggregate + bias + elu + residual(bf16) +
// LN. POOL: additionally compute per-graph meanpool . ro_w -> sigmoid -> out,
// and skip the x writeback (final layer).
template<int H, bool POOL>
__global__ __launch_bounds__(256) void gat_fused(const ushort* __restrict__ h,
    const float* __restrict__ asv, const float* __restrict__ adv,
    const float* __restrict__ bias, const float* __restrict__ lng,
    const float* __restrict__ lnb, ushort* __restrict__ xbb,
    const float* __restrict__ rw, const float* __restrict__ rbias,
    float* __restrict__ out) {
  constexpr int C = 256 / H;
  constexpr int GROUP = C / 4;
  __shared__ __align__(16) float hs[4][8][256];
  __shared__ float attS[4][8][H], attD[4][8][H];
  const int wid = threadIdx.x >> 6, lane = threadIdx.x & 63;
  const int g = blockIdx.x * 4 + wid;
  const int base = g * 8;
  const int hd = lane / GROUP;
  float4 as4 = *reinterpret_cast<const float4*>(asv + lane * 4);
  float4 ad4 = *reinterpret_cast<const float4*>(adv + lane * 4);
#pragma unroll
  for (int i = 0; i < 8; ++i) {
    uint2 raw = *reinterpret_cast<const uint2*>(h + (size_t)(base + i) * 256 + lane * 4);
    float f0 = bf2f_lo(raw.x);
    float f1 = bf2f_hi(raw.x);
    float f2 = bf2f_lo(raw.y);
    float f3 = bf2f_hi(raw.y);
    *reinterpret_cast<float4*>(&hs[wid][i][lane * 4]) = make_float4(f0, f1, f2, f3);
    float ps = f0 * as4.x + f1 * as4.y + f2 * as4.z + f3 * as4.w;
    float pd = f0 * ad4.x + f1 * ad4.y + f2 * ad4.z + f3 * ad4.w;
#pragma unroll
    for (int o = GROUP / 2; o >= 1; o >>= 1) {
      ps += __shfl_xor(ps, o);
      pd += __shfl_xor(pd, o);
    }
    if ((lane & (GROUP - 1)) == 0) {
      attS[wid][i][hd] = ps;
      attD[wid][i][hd] = pd;
    }
  }
  __syncthreads();
  const float4 gv = *reinterpret_cast<const float4*>(lng + lane * 4);
  const float4 bv = *reinterpret_cast<const float4*>(lnb + lane * 4);
  const float4 biasv = *reinterpret_cast<const float4*>(bias + lane * 4);
  float4 rw4 = make_float4(0, 0, 0, 0);
  if (POOL) rw4 = *reinterpret_cast<const float4*>(rw + lane * 4);
  float pr = 0.f;
  for (int i = 0; i < 8; ++i) {
    float ad = attD[wid][i][hd];
    float e[8];
    float mx = -1e30f;
#pragma unroll
    for (int j = 0; j < 8; ++j) {
      float v = attS[wid][j][hd] + ad;
      v = v > 0.f ? v : 0.2f * v;
      e[j] = v;
      mx = fmaxf(mx, v);
    }
    float sum = 0.f;
#pragma unroll
    for (int j = 0; j < 8; ++j) { e[j] = expf(e[j] - mx); sum += e[j]; }
    float inv = 1.f / (sum + 1e-16f);
    float a0 = 0, a1 = 0, a2 = 0, a3 = 0;
#pragma unroll
    for (int j = 0; j < 8; ++j) {
      float wj = e[j] * inv;
      float4 hv = *reinterpret_cast<const float4*>(&hs[wid][j][lane * 4]);
      a0 += wj * hv.x; a1 += wj * hv.y; a2 += wj * hv.z; a3 += wj * hv.w;
    }
    uint2 xr = *reinterpret_cast<const uint2*>(xbb + (size_t)(base + i) * 256 + lane * 4);
    float v0 = elu_f(a0 + biasv.x) + bf2f_lo(xr.x);
    float v1 = elu_f(a1 + biasv.y) + bf2f_hi(xr.x);
    float v2 = elu_f(a2 + biasv.z) + bf2f_lo(xr.y);
    float v3 = elu_f(a3 + biasv.w) + bf2f_hi(xr.y);
    float s = v0 + v1 + v2 + v3;
    float s2 = v0 * v0 + v1 * v1 + v2 * v2 + v3 * v3;
    s = warp_sum(s); s2 = warp_sum(s2);
    float mu = s * (1.f / 256.f);
    float var = s2 * (1.f / 256.f) - mu * mu;
    float rs = rsqrtf(var + 1e-5f);
    float o0 = (v0 - mu) * rs * gv.x + bv.x;
    float o1 = (v1 - mu) * rs * gv.y + bv.y;
    float o2 = (v2 - mu) * rs * gv.z + bv.z;
    float o3 = (v3 - mu) * rs * gv.w + bv.w;
    if (POOL) {
      pr += o0 * rw4.x + o1 * rw4.y + o2 * rw4.z + o3 * rw4.w;
    } else {
      uint2 ob;
      ob.x = pkbf(o0, o1);
      ob.y = pkbf(o2, o3);
      *reinterpret_cast<uint2*>(xbb + (size_t)(base + i) * 256 + lane * 4) = ob;
    }
  }
  if (POOL) {
    pr = warp_sum(pr) * 0.125f;
    if (lane == 0) out[g] = 1.f / (1.f + expf(-(pr + rbias[0])));
  }
}

extern "C" void kernel_launch(void* const* d_in, const int* in_sizes, int n_in,
                              void* d_out, int out_size, void* d_ws, size_t ws_size,
                              hipStream_t stream) {
  const int* cat_ids = (const int*)d_in[0];
  const float* vf = (const float*)d_in[1];
  const float* cat_table = (const float*)d_in[4];
  const float* vp_w1 = (const float*)d_in[5];
  const float* vp_b1 = (const float*)d_in[6];
  const float* vp_w2 = (const float*)d_in[7];
  const float* vp_b2 = (const float*)d_in[8];
  const float* vp_lng = (const float*)d_in[9];
  const float* vp_lnb = (const float*)d_in[10];
  const float* c0_w = (const float*)d_in[11];
  const float* c0_as = (const float*)d_in[12];
  const float* c0_ad = (const float*)d_in[13];
  const float* c0_b = (const float*)d_in[14];
  const float* ln0_g = (const float*)d_in[15];
  const float* ln0_b = (const float*)d_in[16];
  const float* c1_w = (const float*)d_in[17];
  const float* c1_as = (const float*)d_in[18];
  const float* c1_ad = (const float*)d_in[19];
  const float* c1_b = (const float*)d_in[20];
  const float* ln1_g = (const float*)d_in[21];
  const float* ln1_b = (const float*)d_in[22];
  const float* ro_w = (const float*)d_in[23];
  const float* ro_b = (const float*)d_in[24];
  float* out = (float*)d_out;

  char* ws = (char*)d_ws;
  ushort* w1b = (ushort*)ws;   ws += (size_t)512 * 2048 * 2;
  ushort* w2b = (ushort*)ws;   ws += (size_t)128 * 512 * 2;
  ushort* c0wb = (ushort*)ws;  ws += (size_t)256 * 256 * 2;
  ushort* c1wb = (ushort*)ws;  ws += (size_t)256 * 256 * 2;
  ushort* catb = (ushort*)ws;  ws += (size_t)120 * 128 * 2;
  ws = (char*)(((size_t)ws + 255) & ~(size_t)255);
  ushort* v1b = (ushort*)ws;   ws += (size_t)NN * 512 * 2;
  ushort* xbb = (ushort*)ws;   ws += (size_t)NN * 256 * 2;
  ushort* hbb = (ushort*)ws;

  dim3 b256(256), b512(512);
  const int RB = (NN + 127) / 128;          // 782
  const int RBpad = ((RB + 7) / 8) * 8;     // 784

  cvt_bf16<<<1024, b256, 0, stream>>>(vp_w1, w1b, 512 * 2048 / 4);
  cvt_bf16<<<64, b256, 0, stream>>>(vp_w2, w2b, 128 * 512 / 4);
  cvt_bf16<<<64, b256, 0, stream>>>(c0_w, c0wb, 256 * 256 / 4);
  cvt_bf16<<<64, b256, 0, stream>>>(c1_w, c1wb, 256 * 256 / 4);
  cvt_bf16<<<15, b256, 0, stream>>>(cat_table, catb, 120 * 128 / 4);

  // v1 = relu(vf @ w1^T + b1)
  gemm_f32p<true><<<RB, b512, 0, stream>>>(vf, w1b, vp_b1, v1b, NN, 2048);
  // xbb = [cat_emb | LN(v1 @ w2^T + b2)]  (fused)
  gemm_ln<<<RB, b256, 0, stream>>>(v1b, w2b, vp_b2, vp_lng, vp_lnb,
                                   cat_ids, catb, xbb, NN, 512, RB);

  gemm_glds<false, 2><<<RBpad * 2, b256, 0, stream>>>(xbb, c0wb, nullptr, hbb,
                                                      NN, 256, 256, RB);
  gat_fused<4, false><<<NG / 4, b256, 0, stream>>>(hbb, c0_as, c0_ad, c0_b,
                                                   ln0_g, ln0_b, xbb,
                                                   nullptr, nullptr, nullptr);

  gemm_glds<false, 2><<<RBpad * 2, b256, 0, stream>>>(xbb, c1wb, nullptr, hbb,
                                                      NN, 256, 256, RB);
  gat_fused<1, true><<<NG / 4, b256, 0, stream>>>(hbb, c1_as, c1_ad, c1_b,
                                                  ln1_g, ln1_b, xbb,
                                                  ro_w, ro_b, out);
}